// Round 1
// baseline (1154.379 us; speedup 1.0000x reference)
//
#include <hip/hip_runtime.h>
#include <hip/hip_bf16.h>
#include <math.h>

#define NQ 50000
#define NS 50000
#define KK 32
#define CT 67        // 3 coords + 64 feats
#define CP 68        // padded (y[...][67] = 0, wreg[67] = 0)
#define CO 64
#define QPB 4        // queries per block (4 waves, 1 query/wave)
#define STAT_BLOCKS 1024

// ws layout (floats): [0..127] scale/bias ; [128 .. 128+STAT_BLOCKS*128) partials

// MODE 0: compute z, accumulate per-channel sum/sumsq -> block partials in ws
// MODE 1: compute z, apply BN (scale/bias from ws) + leaky + max over k -> out
template <int MODE>
__global__ __launch_bounds__(256) void gc_kernel(
    const float* __restrict__ q_points,
    const float* __restrict__ s_points,
    const float* __restrict__ feat,
    const float* __restrict__ conv_w,
    const int*   __restrict__ inds,
    float* __restrict__ out,
    float* __restrict__ ws)   // MODE0: partials base ; MODE1: scale/bias base
{
    __shared__ float y[QPB][KK][CP];
    __shared__ int   s_idx[QPB][KK];
    __shared__ float red[2][QPB][CO];

    const int tid  = threadIdx.x;
    const int lane = tid & 63;
    const int wv   = tid >> 6;

    // W row for this lane's channel, register-resident
    float wreg[CP];
#pragma unroll
    for (int c = 0; c < CT; ++c) wreg[c] = conv_w[lane * CT + c];
    wreg[CP - 1] = 0.f;

    float scale = 0.f, bias = 0.f;
    if (MODE == 1) { scale = ws[lane]; bias = ws[64 + lane]; }

    float acc_sum = 0.f, acc_sq = 0.f;

    for (int qb = blockIdx.x * QPB; qb < NQ; qb += gridDim.x * QPB) {
        __syncthreads();   // protect LDS from previous iteration's readers

        // stage neighbor indices (QPB*KK = 128 ints)
        if (tid < QPB * KK) {
            int qq = tid / KK, k = tid & (KK - 1);
            int q  = qb + qq;
            s_idx[qq][k] = (q < NQ) ? inds[q * KK + k] : NS;
        }
        __syncthreads();

        // stage feats: QPB*KK*64 = 8192 elements, lane -> channel (coalesced per row)
        for (int e = tid; e < QPB * KK * 64; e += 256) {
            int c  = e & 63;
            int k  = (e >> 6) & (KK - 1);
            int qq = e >> 11;
            int ii = s_idx[qq][k];
            float v = (ii < NS) ? feat[ii * 64 + c] : 0.f;
            y[qq][k][3 + c] = v;
        }
        // stage relative coords (+ zero the pad slot)
        for (int e = tid; e < QPB * KK * 4; e += 256) {
            int c3 = e & 3;
            int k  = (e >> 2) & (KK - 1);
            int qq = e >> 7;
            int q  = qb + qq;
            if (c3 < 3) {
                int ii = s_idx[qq][k];
                float v = 0.f;
                if (q < NQ && ii < NS)
                    v = s_points[ii * 3 + c3] - q_points[q * 3 + c3];
                y[qq][k][c3] = v;
            } else {
                y[qq][k][CP - 1] = 0.f;
            }
        }
        __syncthreads();

        // compute: wave wv owns query qb+wv; lane owns channel `lane`
        int q = qb + wv;
        if (q < NQ) {
            if (MODE == 0) {
                for (int k = 0; k < KK; ++k) {
                    const float* yr = y[wv][k];
                    float a0 = 0.f, a1 = 0.f, a2 = 0.f, a3 = 0.f;
#pragma unroll
                    for (int c = 0; c < CP; c += 4) {
                        a0 += wreg[c + 0] * yr[c + 0];
                        a1 += wreg[c + 1] * yr[c + 1];
                        a2 += wreg[c + 2] * yr[c + 2];
                        a3 += wreg[c + 3] * yr[c + 3];
                    }
                    float z = (a0 + a1) + (a2 + a3);
                    acc_sum += z;
                    acc_sq  += z * z;
                }
            } else {
                float m = -INFINITY;
                for (int k = 0; k < KK; ++k) {
                    const float* yr = y[wv][k];
                    float a0 = 0.f, a1 = 0.f, a2 = 0.f, a3 = 0.f;
#pragma unroll
                    for (int c = 0; c < CP; c += 4) {
                        a0 += wreg[c + 0] * yr[c + 0];
                        a1 += wreg[c + 1] * yr[c + 1];
                        a2 += wreg[c + 2] * yr[c + 2];
                        a3 += wreg[c + 3] * yr[c + 3];
                    }
                    float z = (a0 + a1) + (a2 + a3);
                    z = z * scale + bias;
                    z = (z >= 0.f) ? z : 0.1f * z;
                    m = fmaxf(m, z);
                }
                out[q * CO + lane] = m;
            }
        }
    }

    if (MODE == 0) {
        // deterministic block reduction over the 4 waves
        red[0][wv][lane] = acc_sum;
        red[1][wv][lane] = acc_sq;
        __syncthreads();
        if (tid < CO) {
            float s  = red[0][0][tid] + red[0][1][tid] + red[0][2][tid] + red[0][3][tid];
            float sq = red[1][0][tid] + red[1][1][tid] + red[1][2][tid] + red[1][3][tid];
            ws[blockIdx.x * 128 + tid]      = s;
            ws[blockIdx.x * 128 + 64 + tid] = sq;
        }
    }
}

__global__ void gc_finalize(const float* __restrict__ partials,
                            const float* __restrict__ gamma,
                            const float* __restrict__ beta,
                            float* __restrict__ scale_bias)
{
    int o = threadIdx.x;   // 64 threads
    double s = 0.0, sq = 0.0;
    for (int b = 0; b < STAT_BLOCKS; ++b) {
        s  += (double)partials[b * 128 + o];
        sq += (double)partials[b * 128 + 64 + o];
    }
    const double n = (double)NQ * (double)KK;
    double mean = s / n;
    double var  = sq / n - mean * mean;
    float sc = gamma[o] * (float)(1.0 / sqrt(var + 1e-5));
    float bi = beta[o] - (float)mean * sc;
    scale_bias[o]      = sc;
    scale_bias[64 + o] = bi;
}

extern "C" void kernel_launch(void* const* d_in, const int* in_sizes, int n_in,
                              void* d_out, int out_size, void* d_ws, size_t ws_size,
                              hipStream_t stream) {
    const float* q_points = (const float*)d_in[0];
    const float* s_points = (const float*)d_in[1];
    const float* feat     = (const float*)d_in[2];
    const float* conv_w   = (const float*)d_in[3];
    const float* gamma    = (const float*)d_in[4];
    const float* beta     = (const float*)d_in[5];
    const int*   inds     = (const int*)d_in[6];

    float* ws  = (float*)d_ws;
    float* sb  = ws;          // 128 floats: scale, bias
    float* par = ws + 128;    // STAT_BLOCKS * 128 floats

    gc_kernel<0><<<STAT_BLOCKS, 256, 0, stream>>>(
        q_points, s_points, feat, conv_w, inds, nullptr, par);
    gc_finalize<<<1, 64, 0, stream>>>(par, gamma, beta, sb);
    gc_kernel<1><<<(NQ + QPB - 1) / QPB, 256, 0, stream>>>(
        q_points, s_points, feat, conv_w, inds, (float*)d_out, sb);
}

// Round 2
// 414.159 us; speedup vs baseline: 2.7873x; 2.7873x over previous
//
#include <hip/hip_runtime.h>
#include <hip/hip_bf16.h>
#include <math.h>

#define NQ 50000
#define NS 50000
#define KK 32
#define CF 64      // feat channels
#define CW 67      // conv input channels (3 + 64)
#define CO 64      // output channels
#define WAVES 4
#define GRID 1024
#define QPWAVE 2
#define QPB (WAVES * QPWAVE)              // 8 queries per block
#define NBATCH ((NQ + QPB - 1) / QPB)     // 6250

// Pass A: z = y @ W^T per position; per-channel sum/sumsq partials; per-query
// max (and optionally min) over the 32 neighbors. zmax goes straight to d_out.
template <bool HAS_MIN>
__global__ __launch_bounds__(256) void gc_zmax(
    const float* __restrict__ qp,
    const float* __restrict__ sp,
    const float* __restrict__ feat,
    const float* __restrict__ w,      // [64][67]
    const int*   __restrict__ inds,
    float* __restrict__ zmax,         // d_out [NQ][64]
    float* __restrict__ zmin,         // ws (optional)
    float* __restrict__ partials)     // [GRID][128]
{
    __shared__ float tile[WAVES][64][33];

    const int tid  = threadIdx.x;
    const int lane = tid & 63;
    const int wv   = tid >> 6;
    const int h    = lane >> 5;   // which of the wave's 2 queries
    const int k    = lane & 31;   // neighbor slot

    float sum0 = 0.f, sum1 = 0.f, sq0 = 0.f, sq1 = 0.f;

    for (int b = blockIdx.x; b < NBATCH; b += GRID) {
        const int q = b * QPB + wv * QPWAVE + h;

        // ---- gather y into registers (lane = one (q,k) position) ----
        float y0 = 0.f, y1 = 0.f, y2 = 0.f;
        float4 f[16];
        int ii = NS;
        if (q < NQ) ii = inds[q * KK + k];
        const bool val = (ii < NS) && (q < NQ);
        if (val) {
            y0 = sp[ii * 3 + 0] - qp[q * 3 + 0];
            y1 = sp[ii * 3 + 1] - qp[q * 3 + 1];
            y2 = sp[ii * 3 + 2] - qp[q * 3 + 2];
            const float4* fp = (const float4*)(feat + (size_t)ii * CF);
#pragma unroll
            for (int j = 0; j < 16; ++j) f[j] = fp[j];
        } else {
#pragma unroll
            for (int j = 0; j < 16; ++j) f[j] = make_float4(0.f, 0.f, 0.f, 0.f);
        }

#pragma unroll
        for (int ch = 0; ch < 2; ++ch) {
            // ---- write phase: 32 output channels, W rows via scalar loads ----
#pragma unroll 2
            for (int oo = 0; oo < 32; ++oo) {
                const int o = ch * 32 + oo;
                const float* wr = w + o * CW;   // uniform -> s_load
                float a0 = wr[0] * y0;
                float a1 = wr[1] * y1;
                float a2 = wr[2] * y2;
                float a3 = 0.f;
#pragma unroll
                for (int j = 0; j < 16; ++j) {
                    a0 += wr[3 + 4 * j] * f[j].x;
                    a1 += wr[4 + 4 * j] * f[j].y;
                    a2 += wr[5 + 4 * j] * f[j].z;
                    a3 += wr[6 + 4 * j] * f[j].w;
                }
                tile[wv][lane][oo] = (a0 + a1) + (a2 + a3);
            }
            __syncthreads();

            // ---- consume phase: lane = channel (k + 32*ch), rows = positions ----
            float mA = -1e38f, mB = -1e38f, nA = 1e38f, nB = 1e38f;
            float s = 0.f, qq = 0.f;
#pragma unroll 4
            for (int i = 0; i < 32; ++i) {
                float z = tile[wv][2 * i + h][k];
                s += z;
                qq += z * z;
                if (i < 16) {
                    mA = fmaxf(mA, z);
                    if (HAS_MIN) nA = fminf(nA, z);
                } else {
                    mB = fmaxf(mB, z);
                    if (HAS_MIN) nB = fminf(nB, z);
                }
            }
            if (ch == 0) { sum0 += s; sq0 += qq; }
            else         { sum1 += s; sq1 += qq; }

            const float mAc = fmaxf(mA, __shfl_xor(mA, 32));
            const float mBc = fmaxf(mB, __shfl_xor(mB, 32));
            const int   qs  = b * QPB + wv * QPWAVE + h;
            const int   os  = k + 32 * ch;
            if (qs < NQ) {
                zmax[qs * CO + os] = (lane < 32) ? mAc : mBc;
                if (HAS_MIN) {
                    const float nAc = fminf(nA, __shfl_xor(nA, 32));
                    const float nBc = fminf(nB, __shfl_xor(nB, 32));
                    zmin[qs * CO + os] = (lane < 32) ? nAc : nBc;
                }
            }
            __syncthreads();
        }
    }

    // ---- block-level stat reduction (deterministic) ----
    const float s0f = sum0 + __shfl_xor(sum0, 32);
    const float s1f = sum1 + __shfl_xor(sum1, 32);
    const float q0f = sq0 + __shfl_xor(sq0, 32);
    const float q1f = sq1 + __shfl_xor(sq1, 32);
    __syncthreads();
    float* area = &tile[wv][0][0];
    if (lane < 32) {
        area[lane]       = s0f;
        area[32 + lane]  = s1f;
        area[64 + lane]  = q0f;
        area[96 + lane]  = q1f;
    }
    __syncthreads();
    if (tid < 128) {
        float v = 0.f;
#pragma unroll
        for (int w2 = 0; w2 < WAVES; ++w2) v += (&tile[w2][0][0])[tid];
        partials[blockIdx.x * 128 + tid] = v;
    }
}

__global__ void gc_finalize(const float* __restrict__ partials,
                            const float* __restrict__ gamma,
                            const float* __restrict__ beta,
                            float* __restrict__ scale_bias)
{
    const int o = threadIdx.x;   // 64 threads
    double s = 0.0, sq = 0.0;
    for (int b = 0; b < GRID; ++b) {
        s  += (double)partials[b * 128 + o];
        sq += (double)partials[b * 128 + 64 + o];
    }
    const double n = (double)NQ * (double)KK;
    const double mean = s / n;
    const double var  = sq / n - mean * mean;
    const float sc = gamma[o] * (float)(1.0 / sqrt(var + 1e-5));
    const float bi = beta[o] - (float)mean * sc;
    scale_bias[o]      = sc;
    scale_bias[64 + o] = bi;
}

// Pass C: out = leaky(scale * zext + bias), in place on d_out (float4-wide).
__global__ void gc_bnact(float4* __restrict__ out,
                         const float4* __restrict__ zmin,
                         const float* __restrict__ sb,
                         int has_min)
{
    const int i = blockIdx.x * 256 + threadIdx.x;   // < NQ*CO/4
    const int ob = (i & 15) * 4;
    const float4 s4 = *(const float4*)(sb + ob);
    const float4 b4 = *(const float4*)(sb + 64 + ob);
    float4 z4 = out[i];
    if (has_min) {
        const float4 n4 = zmin[i];
        if (s4.x < 0.f) z4.x = n4.x;
        if (s4.y < 0.f) z4.y = n4.y;
        if (s4.z < 0.f) z4.z = n4.z;
        if (s4.w < 0.f) z4.w = n4.w;
    }
    float4 v;
    v.x = s4.x * z4.x + b4.x;
    v.y = s4.y * z4.y + b4.y;
    v.z = s4.z * z4.z + b4.z;
    v.w = s4.w * z4.w + b4.w;
    v.x = (v.x >= 0.f) ? v.x : 0.1f * v.x;
    v.y = (v.y >= 0.f) ? v.y : 0.1f * v.y;
    v.z = (v.z >= 0.f) ? v.z : 0.1f * v.z;
    v.w = (v.w >= 0.f) ? v.w : 0.1f * v.w;
    out[i] = v;
}

extern "C" void kernel_launch(void* const* d_in, const int* in_sizes, int n_in,
                              void* d_out, int out_size, void* d_ws, size_t ws_size,
                              hipStream_t stream) {
    const float* q_points = (const float*)d_in[0];
    const float* s_points = (const float*)d_in[1];
    const float* feat     = (const float*)d_in[2];
    const float* conv_w   = (const float*)d_in[3];
    const float* gamma    = (const float*)d_in[4];
    const float* beta     = (const float*)d_in[5];
    const int*   inds     = (const int*)d_in[6];

    float* ws  = (float*)d_ws;
    float* sb  = ws;                    // 128 floats
    float* par = ws + 128;              // GRID*128 floats
    float* zmn = ws + 128 + GRID * 128; // NQ*CO floats (optional)

    const size_t need_min = (size_t)(128 + GRID * 128 + NQ * CO) * 4;
    const bool has_min = ws_size >= need_min;

    float* zmax = (float*)d_out;

    if (has_min) {
        gc_zmax<true><<<GRID, 256, 0, stream>>>(
            q_points, s_points, feat, conv_w, inds, zmax, zmn, par);
    } else {
        gc_zmax<false><<<GRID, 256, 0, stream>>>(
            q_points, s_points, feat, conv_w, inds, zmax, nullptr, par);
    }
    gc_finalize<<<1, 64, 0, stream>>>(par, gamma, beta, sb);
    gc_bnact<<<(NQ * CO / 4 + 255) / 256, 256, 0, stream>>>(
        (float4*)d_out, (const float4*)zmn, sb, has_min ? 1 : 0);
}

// Round 4
// 164.303 us; speedup vs baseline: 7.0259x; 2.5207x over previous
//
#include <hip/hip_runtime.h>
#include <hip/hip_bf16.h>
#include <math.h>

#define NQ 50000
#define NS 50000
#define KK 32
#define CF 64      // feat channels
#define CW 67      // conv input channels (3 + 64)
#define CO 64      // output channels
#define WAVES 4
#define GRID 1024

typedef __attribute__((ext_vector_type(8))) short bf16x8;
typedef __attribute__((ext_vector_type(16))) float f32x16;

__device__ inline short f2b(float x) {
    union { float f; unsigned u; } v; v.f = x;
    unsigned r = (v.u + 0x7fffu + ((v.u >> 16) & 1u)) >> 16;
    return (short)r;
}

__device__ inline bf16x8 pack2(const float4 a, const float4 b) {
    bf16x8 r;
    r[0] = f2b(a.x); r[1] = f2b(a.y); r[2] = f2b(a.z); r[3] = f2b(a.w);
    r[4] = f2b(b.x); r[5] = f2b(b.y); r[6] = f2b(b.z); r[7] = f2b(b.w);
    return r;
}

__device__ inline bf16x8 zero8() {
    bf16x8 r;
#pragma unroll
    for (int j = 0; j < 8; ++j) r[j] = 0;
    return r;
}

// One wave = one query per iteration. M=32 neighbors, N=64 (2 tiles of 32),
// K=80 (k0..63 = feat channels, k64..66 = rel coords, k67..79 = zero pad).
// zmax -> d_out directly; global per-channel sum/sumsq -> block partials.
template <bool HAS_MIN>
__global__ __launch_bounds__(256, 3) void gc_mfma(
    const float* __restrict__ qp,
    const float* __restrict__ sp,
    const float* __restrict__ feat,
    const float* __restrict__ w,      // [64][67]
    const int*   __restrict__ inds,
    float* __restrict__ zmax,         // d_out [NQ][64]
    float* __restrict__ zmin,         // ws (optional)
    float* __restrict__ partials)     // [GRID][128]
{
    __shared__ float red[WAVES][128];

    const int tid  = threadIdx.x;
    const int lane = tid & 63;
    const int wv   = tid >> 6;
    const int col  = lane & 31;
    const int half = lane >> 5;

    // ---- B fragments (weights), register-resident, built once ----
    bf16x8 bfrag[5][2];
#pragma unroll
    for (int c = 0; c < 5; ++c) {
#pragma unroll
        for (int t = 0; t < 2; ++t) {
            const int o = t * 32 + col;
            bf16x8 r;
#pragma unroll
            for (int j = 0; j < 8; ++j) {
                const int k = c * 16 + half * 8 + j;
                float v = 0.f;
                if (k < 64)      v = w[o * CW + 3 + k];
                else if (k < 67) v = w[o * CW + (k - 64)];
                r[j] = f2b(v);
            }
            bfrag[c][t] = r;
        }
    }

    float csum0 = 0.f, csum1 = 0.f, csq0 = 0.f, csq1 = 0.f;

    for (int qb = blockIdx.x * WAVES; qb < NQ; qb += GRID * WAVES) {
        const int q = qb + wv;           // NQ % 4 == 0 -> always < NQ

        // ---- gather A fragments (lane: row = col = neighbor slot) ----
        const int  ii  = inds[q * KK + col];
        const bool val = (ii < NS);

        bf16x8 afrag[5];
        if (val) {
            const float4* fp = (const float4*)(feat + (size_t)ii * CF);
#pragma unroll
            for (int c = 0; c < 4; ++c) {
                const float4 u0 = fp[c * 4 + half * 2];
                const float4 u1 = fp[c * 4 + half * 2 + 1];
                afrag[c] = pack2(u0, u1);
            }
            bf16x8 r = zero8();
            if (half == 0) {
                r[0] = f2b(sp[ii * 3 + 0] - qp[q * 3 + 0]);
                r[1] = f2b(sp[ii * 3 + 1] - qp[q * 3 + 1]);
                r[2] = f2b(sp[ii * 3 + 2] - qp[q * 3 + 2]);
            }
            afrag[4] = r;
        } else {
#pragma unroll
            for (int c = 0; c < 5; ++c) afrag[c] = zero8();
        }

        // ---- MFMA: C[32 rows=neighbors][64 cols=channels] ----
        f32x16 acc0, acc1;
#pragma unroll
        for (int r = 0; r < 16; ++r) { acc0[r] = 0.f; acc1[r] = 0.f; }
#pragma unroll
        for (int c = 0; c < 5; ++c) {
            acc0 = __builtin_amdgcn_mfma_f32_32x32x16_bf16(afrag[c], bfrag[c][0], acc0, 0, 0, 0);
            acc1 = __builtin_amdgcn_mfma_f32_32x32x16_bf16(afrag[c], bfrag[c][1], acc1, 0, 0, 0);
        }

        // ---- epilogue: per-col max over 32 rows + sum/sumsq ----
        float m0 = acc0[0], m1 = acc1[0];
        float n0 = acc0[0], n1 = acc1[0];
        float s0 = 0.f, s1 = 0.f, q0 = 0.f, q1 = 0.f;
#pragma unroll
        for (int r = 0; r < 16; ++r) {
            const float z0 = acc0[r], z1 = acc1[r];
            m0 = fmaxf(m0, z0); m1 = fmaxf(m1, z1);
            if (HAS_MIN) { n0 = fminf(n0, z0); n1 = fminf(n1, z1); }
            s0 += z0; s1 += z1;
            q0 = fmaf(z0, z0, q0); q1 = fmaf(z1, z1, q1);
        }
        m0 = fmaxf(m0, __shfl_xor(m0, 32));
        m1 = fmaxf(m1, __shfl_xor(m1, 32));
        csum0 += s0 + __shfl_xor(s0, 32);
        csum1 += s1 + __shfl_xor(s1, 32);
        csq0  += q0 + __shfl_xor(q0, 32);
        csq1  += q1 + __shfl_xor(q1, 32);

        zmax[q * CO + half * 32 + col] = half ? m1 : m0;
        if (HAS_MIN) {
            n0 = fminf(n0, __shfl_xor(n0, 32));
            n1 = fminf(n1, __shfl_xor(n1, 32));
            zmin[q * CO + half * 32 + col] = half ? n1 : n0;
        }
    }

    // ---- block-level stat partials (deterministic) ----
    if (lane < 32) {
        red[wv][col]      = csum0;
        red[wv][32 + col] = csum1;
        red[wv][64 + col] = csq0;
        red[wv][96 + col] = csq1;
    }
    __syncthreads();
    if (tid < 128) {
        const float v = red[0][tid] + red[1][tid] + red[2][tid] + red[3][tid];
        partials[blockIdx.x * 128 + tid] = v;
    }
}

__global__ void gc_finalize(const float* __restrict__ partials,
                            const float* __restrict__ gamma,
                            const float* __restrict__ beta,
                            float* __restrict__ sb)
{
    __shared__ double rs[4][64], rq[4][64];
    const int tid  = threadIdx.x;     // 256
    const int ch   = tid & 63;
    const int part = tid >> 6;
    double s = 0.0, sq = 0.0;
    for (int b = part; b < GRID; b += 4) {
        s  += (double)partials[b * 128 + ch];
        sq += (double)partials[b * 128 + 64 + ch];
    }
    rs[part][ch] = s; rq[part][ch] = sq;
    __syncthreads();
    if (tid < 64) {
        const double st = rs[0][tid] + rs[1][tid] + rs[2][tid] + rs[3][tid];
        const double qt = rq[0][tid] + rq[1][tid] + rq[2][tid] + rq[3][tid];
        const double n = (double)NQ * (double)KK;
        const double mean = st / n;
        const double var  = qt / n - mean * mean;
        const float sc = gamma[tid] * (float)(1.0 / sqrt(var + 1e-5));
        const float bi = beta[tid] - (float)mean * sc;
        sb[tid]      = sc;
        sb[64 + tid] = bi;
    }
}

// out = leaky(scale * z + bias), in place on d_out (float4-wide).
__global__ void gc_bnact(float4* __restrict__ out,
                         const float4* __restrict__ zmin,
                         const float* __restrict__ sb,
                         int has_min)
{
    const int i  = blockIdx.x * 256 + threadIdx.x;   // < NQ*CO/4
    const int ob = (i & 15) * 4;
    const float4 s4 = *(const float4*)(sb + ob);
    const float4 b4 = *(const float4*)(sb + 64 + ob);
    float4 z4 = out[i];
    if (has_min) {
        const float4 n4 = zmin[i];
        if (s4.x < 0.f) z4.x = n4.x;
        if (s4.y < 0.f) z4.y = n4.y;
        if (s4.z < 0.f) z4.z = n4.z;
        if (s4.w < 0.f) z4.w = n4.w;
    }
    float4 v;
    v.x = s4.x * z4.x + b4.x;
    v.y = s4.y * z4.y + b4.y;
    v.z = s4.z * z4.z + b4.z;
    v.w = s4.w * z4.w + b4.w;
    v.x = (v.x >= 0.f) ? v.x : 0.1f * v.x;
    v.y = (v.y >= 0.f) ? v.y : 0.1f * v.y;
    v.z = (v.z >= 0.f) ? v.z : 0.1f * v.z;
    v.w = (v.w >= 0.f) ? v.w : 0.1f * v.w;
    out[i] = v;
}

extern "C" void kernel_launch(void* const* d_in, const int* in_sizes, int n_in,
                              void* d_out, int out_size, void* d_ws, size_t ws_size,
                              hipStream_t stream) {
    const float* q_points = (const float*)d_in[0];
    const float* s_points = (const float*)d_in[1];
    const float* feat     = (const float*)d_in[2];
    const float* conv_w   = (const float*)d_in[3];
    const float* gamma    = (const float*)d_in[4];
    const float* beta     = (const float*)d_in[5];
    const int*   inds     = (const int*)d_in[6];

    float* ws  = (float*)d_ws;
    float* sb  = ws;                    // 128 floats
    float* par = ws + 128;              // GRID*128 floats
    float* zmn = ws + 128 + GRID * 128; // NQ*CO floats (optional)

    const size_t need_min = (size_t)(128 + GRID * 128 + (size_t)NQ * CO) * 4;
    const bool has_min = ws_size >= need_min;

    float* zmax = (float*)d_out;

    if (has_min) {
        gc_mfma<true><<<GRID, 256, 0, stream>>>(
            q_points, s_points, feat, conv_w, inds, zmax, zmn, par);
    } else {
        gc_mfma<false><<<GRID, 256, 0, stream>>>(
            q_points, s_points, feat, conv_w, inds, zmax, nullptr, par);
    }
    gc_finalize<<<1, 256, 0, stream>>>(par, gamma, beta, sb);
    gc_bnact<<<(NQ * CO / 4 + 255) / 256, 256, 0, stream>>>(
        (float4*)d_out, (const float4*)zmn, sb, has_min ? 1 : 0);
}

// Round 5
// 92.906 us; speedup vs baseline: 12.4252x; 1.7685x over previous
//
#include <hip/hip_runtime.h>
#include <hip/hip_bf16.h>
#include <math.h>

#define NQ 50000
#define NS 50000
#define KK 32
#define CF 64      // feat channels
#define CW 67      // conv input channels (3 + 64)
#define CO 64      // output channels
#define WAVES 4
#define GRID 768   // 3 blocks/CU at ~150 VGPR -> balanced residency
#define GS (GRID * WAVES)   // 3072 queries per grid-stride step

typedef __attribute__((ext_vector_type(8))) short bf16x8;
typedef __attribute__((ext_vector_type(16))) float f32x16;

__device__ inline short f2b(float x) {
    union { __hip_bfloat16 b; short s; } u;
    u.b = __float2bfloat16(x);   // RNE; lets compiler pack v_cvt_pk_bf16_f32
    return u.s;
}

__device__ inline bf16x8 pack2(const float4 a, const float4 b) {
    bf16x8 r;
    r[0] = f2b(a.x); r[1] = f2b(a.y); r[2] = f2b(a.z); r[3] = f2b(a.w);
    r[4] = f2b(b.x); r[5] = f2b(b.y); r[6] = f2b(b.z); r[7] = f2b(b.w);
    return r;
}

// One wave = one query per iteration. M=32 neighbors, N=64 (2 tiles of 32),
// K=80 (k0..63 = feat channels, k64..66 = rel coords, pad zero).
// Software-pipelined: indices 2 iterations ahead, feat/coord loads 1 ahead.
template <bool HAS_MIN>
__global__ __launch_bounds__(256, 3) void gc_mfma(
    const float* __restrict__ qp,
    const float* __restrict__ sp,
    const float* __restrict__ feat,
    const float* __restrict__ w,      // [64][67]
    const int*   __restrict__ inds,
    const float* __restrict__ zrow,   // 64 zero floats in ws
    float* __restrict__ zmax,         // d_out [NQ][64]
    float* __restrict__ zmin,         // ws (optional)
    float* __restrict__ partials)     // [GRID][128]
{
    __shared__ float red[WAVES][128];

    const int tid  = threadIdx.x;
    const int lane = tid & 63;
    const int wv   = tid >> 6;
    const int col  = lane & 31;
    const int half = lane >> 5;

    // ---- B fragments (weights), register-resident, built once ----
    bf16x8 bfrag[5][2];
#pragma unroll
    for (int c = 0; c < 5; ++c) {
#pragma unroll
        for (int t = 0; t < 2; ++t) {
            const int o = t * 32 + col;
            bf16x8 r;
#pragma unroll
            for (int j = 0; j < 8; ++j) {
                const int k = c * 16 + half * 8 + j;
                float v = 0.f;
                if (k < 64)      v = w[o * CW + 3 + k];
                else if (k < 67) v = w[o * CW + (k - 64)];
                r[j] = f2b(v);
            }
            bfrag[c][t] = r;
        }
    }

    float csum0 = 0.f, csum1 = 0.f, csq0 = 0.f, csq1 = 0.f;

    // ---- pipeline prologue (q0 < GS <= NQ always) ----
    int q = blockIdx.x * WAVES + wv;
    int i_cur = inds[q * KK + col];
    bool v_cur = (i_cur < NS);
    {
        const float4* fp = (const float4*)(v_cur ? feat + (size_t)i_cur * CF : zrow);
        const float*  spp = v_cur ? sp + (size_t)i_cur * 3 : zrow;
        // declared below in loop scope via F/sx..: use locals here
    }
    float4 F[8];
    float sx, sy, sz, qx, qy, qz;
    {
        const float4* fp = (const float4*)(v_cur ? feat + (size_t)i_cur * CF : zrow);
        const float*  spp = v_cur ? sp + (size_t)i_cur * 3 : zrow;
#pragma unroll
        for (int c = 0; c < 4; ++c) {
            F[2 * c]     = fp[c * 4 + half * 2];
            F[2 * c + 1] = fp[c * 4 + half * 2 + 1];
        }
        sx = spp[0]; sy = spp[1]; sz = spp[2];
        qx = qp[q * 3 + 0]; qy = qp[q * 3 + 1]; qz = qp[q * 3 + 2];
    }
    int qn = q + GS;
    int i_nxt = 0;
    if (qn < NQ) i_nxt = inds[qn * KK + col];

    while (true) {
        // ---- pack current query's A fragments (waits on F/coords) ----
        bf16x8 afrag[5];
#pragma unroll
        for (int c = 0; c < 4; ++c)
            afrag[c] = pack2(F[2 * c], F[2 * c + 1]);
        {
            bf16x8 r;
#pragma unroll
            for (int j = 0; j < 8; ++j) r[j] = 0;
            if (half == 0) {
                r[0] = f2b(v_cur ? sx - qx : 0.f);
                r[1] = f2b(v_cur ? sy - qy : 0.f);
                r[2] = f2b(v_cur ? sz - qz : 0.f);
            }
            afrag[4] = r;
        }

        // ---- issue next query's gather (overlaps MFMA + epilogue) ----
        const bool have_next = (qn < NQ);   // wave-uniform
        bool v_nxt = false;
        int  i_fut = 0;
        if (have_next) {
            v_nxt = (i_nxt < NS);
            const float4* fpn = (const float4*)(v_nxt ? feat + (size_t)i_nxt * CF : zrow);
            const float*  spn = v_nxt ? sp + (size_t)i_nxt * 3 : zrow;
#pragma unroll
            for (int c = 0; c < 4; ++c) {
                F[2 * c]     = fpn[c * 4 + half * 2];
                F[2 * c + 1] = fpn[c * 4 + half * 2 + 1];
            }
            sx = spn[0]; sy = spn[1]; sz = spn[2];
            qx = qp[qn * 3 + 0]; qy = qp[qn * 3 + 1]; qz = qp[qn * 3 + 2];
            const int qn2 = qn + GS;
            if (qn2 < NQ) i_fut = inds[qn2 * KK + col];
        }

        // ---- MFMA: C[32 rows=neighbors][64 cols=channels] ----
        f32x16 acc0, acc1;
#pragma unroll
        for (int r = 0; r < 16; ++r) { acc0[r] = 0.f; acc1[r] = 0.f; }
#pragma unroll
        for (int c = 0; c < 5; ++c) {
            acc0 = __builtin_amdgcn_mfma_f32_32x32x16_bf16(afrag[c], bfrag[c][0], acc0, 0, 0, 0);
            acc1 = __builtin_amdgcn_mfma_f32_32x32x16_bf16(afrag[c], bfrag[c][1], acc1, 0, 0, 0);
        }

        // ---- epilogue: per-col max over 32 rows + sum/sumsq ----
        float m0 = acc0[0], m1 = acc1[0];
        float n0 = acc0[0], n1 = acc1[0];
        float s0 = 0.f, s1 = 0.f, q0 = 0.f, q1 = 0.f;
#pragma unroll
        for (int r = 0; r < 16; ++r) {
            const float z0 = acc0[r], z1 = acc1[r];
            m0 = fmaxf(m0, z0); m1 = fmaxf(m1, z1);
            if (HAS_MIN) { n0 = fminf(n0, z0); n1 = fminf(n1, z1); }
            s0 += z0; s1 += z1;
            q0 = fmaf(z0, z0, q0); q1 = fmaf(z1, z1, q1);
        }
        csum0 += s0; csum1 += s1; csq0 += q0; csq1 += q1;   // per-lane; reduce at end

        m0 = fmaxf(m0, __shfl_xor(m0, 32));
        m1 = fmaxf(m1, __shfl_xor(m1, 32));
        zmax[q * CO + half * 32 + col] = half ? m1 : m0;
        if (HAS_MIN) {
            n0 = fminf(n0, __shfl_xor(n0, 32));
            n1 = fminf(n1, __shfl_xor(n1, 32));
            zmin[q * CO + half * 32 + col] = half ? n1 : n0;
        }

        if (!have_next) break;
        q = qn; qn = qn + GS;
        i_cur = i_nxt; i_nxt = i_fut; v_cur = v_nxt;
    }

    // ---- block-level stat partials (deterministic) ----
    csum0 += __shfl_xor(csum0, 32);
    csum1 += __shfl_xor(csum1, 32);
    csq0  += __shfl_xor(csq0, 32);
    csq1  += __shfl_xor(csq1, 32);
    if (lane < 32) {
        red[wv][col]      = csum0;
        red[wv][32 + col] = csum1;
        red[wv][64 + col] = csq0;
        red[wv][96 + col] = csq1;
    }
    __syncthreads();
    if (tid < 128) {
        const float v = red[0][tid] + red[1][tid] + red[2][tid] + red[3][tid];
        partials[blockIdx.x * 128 + tid] = v;
    }
}

// One block per channel: deterministic tree reduction over GRID partials.
__global__ void gc_finalize(const float* __restrict__ partials,
                            const float* __restrict__ gamma,
                            const float* __restrict__ beta,
                            float* __restrict__ sb)
{
    __shared__ double rs[256], rq[256];
    const int o = blockIdx.x;     // channel
    const int t = threadIdx.x;    // 256
    double s = 0.0, qq = 0.0;
    for (int b = t; b < GRID; b += 256) {
        s  += (double)partials[b * 128 + o];
        qq += (double)partials[b * 128 + 64 + o];
    }
    rs[t] = s; rq[t] = qq;
    __syncthreads();
    for (int w2 = 128; w2 > 0; w2 >>= 1) {
        if (t < w2) { rs[t] += rs[t + w2]; rq[t] += rq[t + w2]; }
        __syncthreads();
    }
    if (t == 0) {
        const double n = (double)NQ * (double)KK;
        const double mean = rs[0] / n;
        const double var  = rq[0] / n - mean * mean;
        const float sc = gamma[o] * (float)(1.0 / sqrt(var + 1e-5));
        const float bi = beta[o] - (float)mean * sc;
        sb[o]      = sc;
        sb[64 + o] = bi;
    }
}

// out = leaky(scale * z + bias), in place on d_out (float4-wide).
__global__ void gc_bnact(float4* __restrict__ out,
                         const float4* __restrict__ zmin,
                         const float* __restrict__ sb,
                         int has_min)
{
    const int i  = blockIdx.x * 256 + threadIdx.x;   // < NQ*CO/4
    const int ob = (i & 15) * 4;
    const float4 s4 = *(const float4*)(sb + ob);
    const float4 b4 = *(const float4*)(sb + 64 + ob);
    float4 z4 = out[i];
    if (has_min) {
        const float4 n4 = zmin[i];
        if (s4.x < 0.f) z4.x = n4.x;
        if (s4.y < 0.f) z4.y = n4.y;
        if (s4.z < 0.f) z4.z = n4.z;
        if (s4.w < 0.f) z4.w = n4.w;
    }
    float4 v;
    v.x = s4.x * z4.x + b4.x;
    v.y = s4.y * z4.y + b4.y;
    v.z = s4.z * z4.z + b4.z;
    v.w = s4.w * z4.w + b4.w;
    v.x = (v.x >= 0.f) ? v.x : 0.1f * v.x;
    v.y = (v.y >= 0.f) ? v.y : 0.1f * v.y;
    v.z = (v.z >= 0.f) ? v.z : 0.1f * v.z;
    v.w = (v.w >= 0.f) ? v.w : 0.1f * v.w;
    out[i] = v;
}

extern "C" void kernel_launch(void* const* d_in, const int* in_sizes, int n_in,
                              void* d_out, int out_size, void* d_ws, size_t ws_size,
                              hipStream_t stream) {
    const float* q_points = (const float*)d_in[0];
    const float* s_points = (const float*)d_in[1];
    const float* feat     = (const float*)d_in[2];
    const float* conv_w   = (const float*)d_in[3];
    const float* gamma    = (const float*)d_in[4];
    const float* beta     = (const float*)d_in[5];
    const int*   inds     = (const int*)d_in[6];

    float* ws   = (float*)d_ws;
    float* sb   = ws;                          // 128 floats
    float* par  = ws + 128;                    // GRID*128 floats
    float* zrow = ws + 128 + GRID * 128;       // 64 zero floats (16B aligned)
    float* zmn  = zrow + 64;                   // NQ*CO floats (optional)

    const size_t need_min = (size_t)(128 + GRID * 128 + 64 + (size_t)NQ * CO) * 4;
    const bool has_min = ws_size >= need_min;

    float* zmax = (float*)d_out;

    hipMemsetAsync(zrow, 0, 64 * sizeof(float), stream);

    if (has_min) {
        gc_mfma<true><<<GRID, 256, 0, stream>>>(
            q_points, s_points, feat, conv_w, inds, zrow, zmax, zmn, par);
    } else {
        gc_mfma<false><<<GRID, 256, 0, stream>>>(
            q_points, s_points, feat, conv_w, inds, zrow, zmax, nullptr, par);
    }
    gc_finalize<<<64, 256, 0, stream>>>(par, gamma, beta, sb);
    gc_bnact<<<(NQ * CO / 4 + 255) / 256, 256, 0, stream>>>(
        (float4*)d_out, (const float4*)zmn, sb, has_min ? 1 : 0);
}